// Round 2
// baseline (74.318 us; speedup 1.0000x reference)
//
#include <hip/hip_runtime.h>
#include <math.h>

#define B_ 16
#define S_ 4
#define T_ 1000
#define D_ 256
#define N_ 8192
#define V_ 50000

constexpr int NC1 = 20;              // chunks over T for k1
constexpr int TC1 = (T_ + NC1 - 1) / NC1;  // 50 frames per chunk
constexpr int NC3 = 128;             // chunks over N for k3
constexpr int CPB3 = N_ / NC3;       // 64 candidates per block

// ws layout (float units)
constexpr size_t OFF_W   = 0;                          // [B*S][NC1][D]  partial wavg
constexpr size_t OFF_CNT = OFF_W   + (size_t)B_*S_*NC1*D_;   // [B*S][NC1]  partial active counts
constexpr size_t OFF_E   = OFF_CNT + (size_t)B_*S_*NC1;      // [B*S][D]    unit e vectors
constexpr size_t OFF_IDX = OFF_E   + (size_t)B_*S_*D_;       // [B*S] ints  target candidate index
constexpr size_t OFF_ACT = OFF_IDX + (size_t)B_*S_;          // [B*S]       active flag (count)
constexpr size_t OFF_DT  = OFF_ACT + (size_t)B_*S_;          // [B*S]       d at target index
constexpr size_t OFF_SE  = OFF_DT  + (size_t)B_*S_;          // [B][NC3][S] partial sum-exp
constexpr size_t WS_FLOATS = OFF_SE + (size_t)B_*NC3*S_;

// ---------------------------------------------------------------- kernel 1
// grid: (B*S*NC1) blocks x 256 threads. One wave = one frame row (64x float4).
__global__ __launch_bounds__(256) void k1_frames(
    const float* __restrict__ spks, const float* __restrict__ ts,
    const int* __restrict__ sigmas, const int* __restrict__ ilens,
    float* __restrict__ Wp, float* __restrict__ Cp)
{
    const int blk   = blockIdx.x;
    const int bs    = blk / NC1;
    const int chunk = blk % NC1;
    const int b = bs / S_, s = bs % S_;
    const int sig  = sigmas[b * S_ + s];
    const int ilen = ilens[b];
    const int t0 = chunk * TC1;
    int t1 = t0 + TC1; if (t1 > T_) t1 = T_; if (t1 > ilen) t1 = ilen;

    const int wid  = threadIdx.x >> 6;
    const int lane = threadIdx.x & 63;

    float4 acc = make_float4(0.f, 0.f, 0.f, 0.f);
    float  cnt = 0.f;
    const float* base = spks + (size_t)bs * T_ * D_;

    for (int t = t0 + wid; t < t1; t += 4) {
        float4 v = *(const float4*)(base + (size_t)t * D_ + lane * 4);
        float n2 = v.x * v.x + v.y * v.y + v.z * v.z + v.w * v.w;
        #pragma unroll
        for (int o = 32; o >= 1; o >>= 1) n2 += __shfl_xor(n2, o, 64);
        const float w = ts[(b * T_ + t) * S_ + sig];
        const float scale = w / sqrtf(n2);
        acc.x += v.x * scale; acc.y += v.y * scale;
        acc.z += v.z * scale; acc.w += v.w * scale;
        if (lane == 0) cnt += rintf(w);
    }

    __shared__ float sacc[4][D_];
    __shared__ float scnt[4];
    sacc[wid][lane * 4 + 0] = acc.x;
    sacc[wid][lane * 4 + 1] = acc.y;
    sacc[wid][lane * 4 + 2] = acc.z;
    sacc[wid][lane * 4 + 3] = acc.w;
    if (lane == 0) scnt[wid] = cnt;
    __syncthreads();

    const int d = threadIdx.x;
    const float sum = sacc[0][d] + sacc[1][d] + sacc[2][d] + sacc[3][d];
    Wp[((size_t)bs * NC1 + chunk) * D_ + d] = sum;
    if (threadIdx.x == 0)
        Cp[(size_t)bs * NC1 + chunk] = scnt[0] + scnt[1] + scnt[2] + scnt[3];
}

// ---------------------------------------------------------------- kernel 2
// grid: (B*S) blocks x 256 threads. Reduce chunks -> unit e; idx; active.
__global__ __launch_bounds__(256) void k2_evec(
    const float* __restrict__ Wp, const float* __restrict__ Cp,
    const int* __restrict__ ss, const int* __restrict__ sigmas,
    float* __restrict__ E, int* __restrict__ IDX, float* __restrict__ ACT)
{
    const int bs = blockIdx.x;
    const int d  = threadIdx.x;
    float sum = 0.f;
    for (int c = 0; c < NC1; ++c) sum += Wp[((size_t)bs * NC1 + c) * D_ + d];

    float n2 = sum * sum;
    #pragma unroll
    for (int o = 32; o >= 1; o >>= 1) n2 += __shfl_xor(n2, o, 64);
    __shared__ float wsum[4];
    if ((threadIdx.x & 63) == 0) wsum[threadIdx.x >> 6] = n2;
    __syncthreads();
    const float tot = wsum[0] + wsum[1] + wsum[2] + wsum[3];

    E[(size_t)bs * D_ + d] = sum / sqrtf(tot);

    if (threadIdx.x == 0) {
        float c = 0.f;
        for (int i = 0; i < NC1; ++i) c += Cp[(size_t)bs * NC1 + i];
        ACT[bs] = c;
        const int b = bs / S_, s = bs % S_;
        IDX[bs] = ss[b * S_ + sigmas[b * S_ + s]];
    }
}

// ---------------------------------------------------------------- kernel 3
// grid: (B*NC3) blocks x 256 threads. One wave = one candidate row.
__global__ __launch_bounds__(256) void k3_dist(
    const float* __restrict__ table, const int* __restrict__ ns,
    const float* __restrict__ E, const int* __restrict__ IDX,
    const float* __restrict__ alpha_p, const float* __restrict__ beta_p,
    float* __restrict__ DT, float* __restrict__ SE)
{
    const int blk   = blockIdx.x;
    const int b     = blk / NC3;
    const int chunk = blk % NC3;
    const int wid  = threadIdx.x >> 6;
    const int lane = threadIdx.x & 63;

    __shared__ float e_s[S_ * D_];
    for (int i = threadIdx.x; i < S_ * D_; i += 256)
        e_s[i] = E[(size_t)b * S_ * D_ + i];
    __syncthreads();

    const float alpha = fmaxf(alpha_p[0], 2.220446049250313e-16f);
    const float beta  = beta_p[0];
    int tgt[S_];
    #pragma unroll
    for (int s2 = 0; s2 < S_; ++s2) tgt[s2] = IDX[b * S_ + s2];

    float se[S_] = {0.f, 0.f, 0.f, 0.f};
    const int n0 = chunk * CPB3;

    for (int c = wid; c < CPB3; c += 4) {
        const int n  = n0 + c;
        const int id = ns[b * N_ + n];
        float4 v = *(const float4*)(table + (size_t)id * D_ + lane * 4);
        float n2 = v.x * v.x + v.y * v.y + v.z * v.z + v.w * v.w;
        float dp[S_];
        #pragma unroll
        for (int s2 = 0; s2 < S_; ++s2) {
            const float* ep = e_s + s2 * D_ + lane * 4;
            dp[s2] = ep[0] * v.x + ep[1] * v.y + ep[2] * v.z + ep[3] * v.w;
        }
        #pragma unroll
        for (int o = 32; o >= 1; o >>= 1) {
            n2 += __shfl_xor(n2, o, 64);
            #pragma unroll
            for (int s2 = 0; s2 < S_; ++s2) dp[s2] += __shfl_xor(dp[s2], o, 64);
        }
        const float invn = 1.f / sqrtf(n2);
        #pragma unroll
        for (int s2 = 0; s2 < S_; ++s2) {
            const float cosv  = dp[s2] * invn;
            const float dist2 = fmaxf(2.f - 2.f * cosv, 0.f);
            const float dd    = alpha * dist2 + beta;
            se[s2] += expf(-dd);
            if (lane == 0 && n == tgt[s2]) DT[b * S_ + s2] = dd;
        }
    }

    __shared__ float sse[4][S_];
    if (lane == 0) {
        #pragma unroll
        for (int s2 = 0; s2 < S_; ++s2) sse[wid][s2] = se[s2];
    }
    __syncthreads();
    if (threadIdx.x < S_) {
        const int s2 = threadIdx.x;
        SE[((size_t)b * NC3 + chunk) * S_ + s2] =
            sse[0][s2] + sse[1][s2] + sse[2][s2] + sse[3][s2];
    }
}

// ---------------------------------------------------------------- kernel 4
// 1 block x 64 threads: finalize loss, mean over (B*S).
__global__ __launch_bounds__(64) void k4_final(
    const float* __restrict__ SE, const float* __restrict__ DT,
    const float* __restrict__ ACT, float* __restrict__ out)
{
    const int bs = threadIdx.x;           // 0..63
    const int b = bs / S_, s = bs % S_;
    double sum = 0.0;
    for (int c = 0; c < NC3; ++c) sum += (double)SE[((size_t)b * NC3 + c) * S_ + s];
    float loss = DT[bs] + (float)log(sum);
    if (!(ACT[bs] > 0.f)) loss = 0.f;
    float v = loss;
    #pragma unroll
    for (int o = 32; o >= 1; o >>= 1) v += __shfl_xor(v, o, 64);
    if (bs == 0) out[0] = v / 64.f;
}

// ---------------------------------------------------------------- launch
extern "C" void kernel_launch(void* const* d_in, const int* in_sizes, int n_in,
                              void* d_out, int out_size, void* d_ws, size_t ws_size,
                              hipStream_t stream)
{
    const float* spks   = (const float*)d_in[0];
    // d_in[1] = ys (unused)
    const float* ts     = (const float*)d_in[2];
    const int*   ss     = (const int*)  d_in[3];
    const int*   sigmas = (const int*)  d_in[4];
    const int*   ns     = (const int*)  d_in[5];
    const int*   ilens  = (const int*)  d_in[6];
    const float* table  = (const float*)d_in[7];
    const float* alpha  = (const float*)d_in[8];
    const float* beta   = (const float*)d_in[9];
    float* out = (float*)d_out;

    float* ws = (float*)d_ws;
    float* Wp  = ws + OFF_W;
    float* Cp  = ws + OFF_CNT;
    float* E   = ws + OFF_E;
    int*   IDX = (int*)(ws + OFF_IDX);
    float* ACT = ws + OFF_ACT;
    float* DT  = ws + OFF_DT;
    float* SE  = ws + OFF_SE;

    k1_frames<<<B_ * S_ * NC1, 256, 0, stream>>>(spks, ts, sigmas, ilens, Wp, Cp);
    k2_evec  <<<B_ * S_,       256, 0, stream>>>(Wp, Cp, ss, sigmas, E, IDX, ACT);
    k3_dist  <<<B_ * NC3,      256, 0, stream>>>(table, ns, E, IDX, alpha, beta, DT, SE);
    k4_final <<<1,              64, 0, stream>>>(SE, DT, ACT, out);
}

// Round 3
// 47.441 us; speedup vs baseline: 1.5665x; 1.5665x over previous
//
#include <hip/hip_runtime.h>
#include <math.h>

#define B_ 16
#define S_ 4
#define T_ 1000
#define D_ 256
#define N_ 8192
#define V_ 50000

constexpr int NC1 = 20;              // chunks over T for k1
constexpr int TC1 = (T_ + NC1 - 1) / NC1;  // 50 frames per chunk
constexpr int CPB3 = 256;            // candidates per block in k3 (1 lane = 1 candidate)
constexpr int NC3 = N_ / CPB3;       // 32 chunks over N

// ws layout (float units)
constexpr size_t OFF_W   = 0;                          // [B*S][NC1][D]  partial wavg
constexpr size_t OFF_CNT = OFF_W   + (size_t)B_*S_*NC1*D_;   // [B*S][NC1]  partial active counts
constexpr size_t OFF_E   = OFF_CNT + (size_t)B_*S_*NC1;      // [B*S][D]    unit e vectors
constexpr size_t OFF_IDX = OFF_E   + (size_t)B_*S_*D_;       // [B*S] ints  target candidate index
constexpr size_t OFF_ACT = OFF_IDX + (size_t)B_*S_;          // [B*S]       active flag (count)
constexpr size_t OFF_DT  = OFF_ACT + (size_t)B_*S_;          // [B*S]       d at target index
constexpr size_t OFF_SE  = OFF_DT  + (size_t)B_*S_;          // [B][NC3][S] partial sum-exp
constexpr size_t WS_FLOATS = OFF_SE + (size_t)B_*NC3*S_;

// ---------------------------------------------------------------- kernel 1
// grid: (B*S*NC1) blocks x 256 threads. One wave = one frame row (64x float4).
__global__ __launch_bounds__(256) void k1_frames(
    const float* __restrict__ spks, const float* __restrict__ ts,
    const int* __restrict__ sigmas, const int* __restrict__ ilens,
    float* __restrict__ Wp, float* __restrict__ Cp)
{
    const int blk   = blockIdx.x;
    const int bs    = blk / NC1;
    const int chunk = blk % NC1;
    const int b = bs / S_, s = bs % S_;
    const int sig  = sigmas[b * S_ + s];
    const int ilen = ilens[b];
    const int t0 = chunk * TC1;
    int t1 = t0 + TC1; if (t1 > T_) t1 = T_; if (t1 > ilen) t1 = ilen;

    const int wid  = threadIdx.x >> 6;
    const int lane = threadIdx.x & 63;

    float4 acc = make_float4(0.f, 0.f, 0.f, 0.f);
    float  cnt = 0.f;
    const float* base = spks + (size_t)bs * T_ * D_;

    for (int t = t0 + wid; t < t1; t += 4) {
        float4 v = *(const float4*)(base + (size_t)t * D_ + lane * 4);
        float n2 = v.x * v.x + v.y * v.y + v.z * v.z + v.w * v.w;
        #pragma unroll
        for (int o = 32; o >= 1; o >>= 1) n2 += __shfl_xor(n2, o, 64);
        const float w = ts[(b * T_ + t) * S_ + sig];
        const float scale = w / sqrtf(n2);
        acc.x += v.x * scale; acc.y += v.y * scale;
        acc.z += v.z * scale; acc.w += v.w * scale;
        if (lane == 0) cnt += rintf(w);
    }

    __shared__ float sacc[4][D_];
    __shared__ float scnt[4];
    sacc[wid][lane * 4 + 0] = acc.x;
    sacc[wid][lane * 4 + 1] = acc.y;
    sacc[wid][lane * 4 + 2] = acc.z;
    sacc[wid][lane * 4 + 3] = acc.w;
    if (lane == 0) scnt[wid] = cnt;
    __syncthreads();

    const int d = threadIdx.x;
    const float sum = sacc[0][d] + sacc[1][d] + sacc[2][d] + sacc[3][d];
    Wp[((size_t)bs * NC1 + chunk) * D_ + d] = sum;
    if (threadIdx.x == 0)
        Cp[(size_t)bs * NC1 + chunk] = scnt[0] + scnt[1] + scnt[2] + scnt[3];
}

// ---------------------------------------------------------------- kernel 2
// grid: (B*S) blocks x 256 threads. Reduce chunks -> unit e; idx; active.
__global__ __launch_bounds__(256) void k2_evec(
    const float* __restrict__ Wp, const float* __restrict__ Cp,
    const int* __restrict__ ss, const int* __restrict__ sigmas,
    float* __restrict__ E, int* __restrict__ IDX, float* __restrict__ ACT)
{
    const int bs = blockIdx.x;
    const int d  = threadIdx.x;
    float sum = 0.f;
    for (int c = 0; c < NC1; ++c) sum += Wp[((size_t)bs * NC1 + c) * D_ + d];

    float n2 = sum * sum;
    #pragma unroll
    for (int o = 32; o >= 1; o >>= 1) n2 += __shfl_xor(n2, o, 64);
    __shared__ float wsum[4];
    if ((threadIdx.x & 63) == 0) wsum[threadIdx.x >> 6] = n2;
    __syncthreads();
    const float tot = wsum[0] + wsum[1] + wsum[2] + wsum[3];

    E[(size_t)bs * D_ + d] = sum / sqrtf(tot);

    if (threadIdx.x == 0) {
        float c = 0.f;
        for (int i = 0; i < NC1; ++i) c += Cp[(size_t)bs * NC1 + i];
        ACT[bs] = c;
        const int b = bs / S_, s = bs % S_;
        IDX[bs] = ss[b * S_ + sigmas[b * S_ + s]];
    }
}

// ---------------------------------------------------------------- kernel 3
// grid: (B*NC3) blocks x 256 threads. ONE LANE = ONE CANDIDATE (no per-row
// cross-lane reduction; e-vector LDS reads are wave-uniform -> broadcast).
__global__ __launch_bounds__(256) void k3_dist(
    const float* __restrict__ table, const int* __restrict__ ns,
    const float* __restrict__ E, const int* __restrict__ IDX,
    const float* __restrict__ alpha_p, const float* __restrict__ beta_p,
    float* __restrict__ DT, float* __restrict__ SE)
{
    const int b     = blockIdx.x / NC3;
    const int chunk = blockIdx.x % NC3;
    const int wid  = threadIdx.x >> 6;
    const int lane = threadIdx.x & 63;

    __shared__ float e_s[S_ * D_];
    for (int i = threadIdx.x; i < S_ * D_; i += 256)
        e_s[i] = E[(size_t)b * S_ * D_ + i];
    __syncthreads();

    const float alpha = fmaxf(alpha_p[0], 2.220446049250313e-16f);
    const float beta  = beta_p[0];
    int tgt[S_];
    #pragma unroll
    for (int s2 = 0; s2 < S_; ++s2) tgt[s2] = IDX[b * S_ + s2];

    const int n  = chunk * CPB3 + threadIdx.x;
    const int id = ns[b * N_ + n];
    const float* __restrict__ row = table + (size_t)id * D_;

    float n2 = 0.f;
    float dp[S_] = {0.f, 0.f, 0.f, 0.f};
    #pragma unroll 4
    for (int d = 0; d < D_; d += 4) {
        const float4 v = *(const float4*)(row + d);
        n2 += v.x * v.x + v.y * v.y + v.z * v.z + v.w * v.w;
        #pragma unroll
        for (int s2 = 0; s2 < S_; ++s2) {
            const float4 e4 = *(const float4*)(e_s + s2 * D_ + d);  // uniform addr: broadcast
            dp[s2] += e4.x * v.x + e4.y * v.y + e4.z * v.z + e4.w * v.w;
        }
    }

    const float invn = 1.f / sqrtf(n2);
    float se[S_];
    #pragma unroll
    for (int s2 = 0; s2 < S_; ++s2) {
        const float cosv  = dp[s2] * invn;
        const float dist2 = fmaxf(2.f - 2.f * cosv, 0.f);
        const float dd    = alpha * dist2 + beta;
        se[s2] = expf(-dd);
        if (n == tgt[s2]) DT[b * S_ + s2] = dd;   // unique writer per (b,s2)
    }

    // block-reduce se[4] over 256 threads (once per 256 candidates)
    #pragma unroll
    for (int o = 32; o >= 1; o >>= 1) {
        #pragma unroll
        for (int s2 = 0; s2 < S_; ++s2) se[s2] += __shfl_xor(se[s2], o, 64);
    }
    __shared__ float sse[4][S_];
    if (lane == 0) {
        #pragma unroll
        for (int s2 = 0; s2 < S_; ++s2) sse[wid][s2] = se[s2];
    }
    __syncthreads();
    if (threadIdx.x < S_) {
        const int s2 = threadIdx.x;
        SE[((size_t)b * NC3 + chunk) * S_ + s2] =
            sse[0][s2] + sse[1][s2] + sse[2][s2] + sse[3][s2];
    }
}

// ---------------------------------------------------------------- kernel 4
// 1 block x 64 threads: finalize loss, mean over (B*S).
__global__ __launch_bounds__(64) void k4_final(
    const float* __restrict__ SE, const float* __restrict__ DT,
    const float* __restrict__ ACT, float* __restrict__ out)
{
    const int bs = threadIdx.x;           // 0..63
    const int b = bs / S_, s = bs % S_;
    double sum = 0.0;
    for (int c = 0; c < NC3; ++c) sum += (double)SE[((size_t)b * NC3 + c) * S_ + s];
    float loss = DT[bs] + (float)log(sum);
    if (!(ACT[bs] > 0.f)) loss = 0.f;
    float v = loss;
    #pragma unroll
    for (int o = 32; o >= 1; o >>= 1) v += __shfl_xor(v, o, 64);
    if (bs == 0) out[0] = v / 64.f;
}

// ---------------------------------------------------------------- launch
extern "C" void kernel_launch(void* const* d_in, const int* in_sizes, int n_in,
                              void* d_out, int out_size, void* d_ws, size_t ws_size,
                              hipStream_t stream)
{
    const float* spks   = (const float*)d_in[0];
    // d_in[1] = ys (unused)
    const float* ts     = (const float*)d_in[2];
    const int*   ss     = (const int*)  d_in[3];
    const int*   sigmas = (const int*)  d_in[4];
    const int*   ns     = (const int*)  d_in[5];
    const int*   ilens  = (const int*)  d_in[6];
    const float* table  = (const float*)d_in[7];
    const float* alpha  = (const float*)d_in[8];
    const float* beta   = (const float*)d_in[9];
    float* out = (float*)d_out;

    float* ws = (float*)d_ws;
    float* Wp  = ws + OFF_W;
    float* Cp  = ws + OFF_CNT;
    float* E   = ws + OFF_E;
    int*   IDX = (int*)(ws + OFF_IDX);
    float* ACT = ws + OFF_ACT;
    float* DT  = ws + OFF_DT;
    float* SE  = ws + OFF_SE;

    k1_frames<<<B_ * S_ * NC1, 256, 0, stream>>>(spks, ts, sigmas, ilens, Wp, Cp);
    k2_evec  <<<B_ * S_,       256, 0, stream>>>(Wp, Cp, ss, sigmas, E, IDX, ACT);
    k3_dist  <<<B_ * NC3,      256, 0, stream>>>(table, ns, E, IDX, alpha, beta, DT, SE);
    k4_final <<<1,              64, 0, stream>>>(SE, DT, ACT, out);
}